// Round 1
// baseline (517.053 us; speedup 1.0000x reference)
//
#include <hip/hip_runtime.h>

typedef __attribute__((ext_vector_type(8))) short bf16x8;
typedef __attribute__((ext_vector_type(4))) float f32x4;

__device__ __forceinline__ unsigned short f2bf(float f) {
    unsigned int u = __builtin_bit_cast(unsigned int, f);
    u += 0x7FFFu + ((u >> 16) & 1u);   // round-to-nearest-even
    return (unsigned short)(u >> 16);
}

// ---------------------------------------------------------------- W1 -> bf16 transposed [128][1024]
__global__ __launch_bounds__(256) void w1t_kernel(const float* __restrict__ W1,
                                                  unsigned short* __restrict__ W1t) {
    __shared__ float tile[32][33];
    const int k0 = blockIdx.x * 32;   // 0..992
    const int n0 = blockIdx.y * 32;   // 0..96
    const int t = threadIdx.x;
    {
        int kr = t >> 3, n4 = (t & 7) * 4;
        float4 v = *(const float4*)(W1 + (size_t)(k0 + kr) * 128 + n0 + n4);
        tile[kr][n4 + 0] = v.x; tile[kr][n4 + 1] = v.y;
        tile[kr][n4 + 2] = v.z; tile[kr][n4 + 3] = v.w;
    }
    __syncthreads();
    {
        int nr = t >> 3, k4 = (t & 7) * 4;
        ushort4 o;
        o.x = f2bf(tile[k4 + 0][nr]);
        o.y = f2bf(tile[k4 + 1][nr]);
        o.z = f2bf(tile[k4 + 2][nr]);
        o.w = f2bf(tile[k4 + 3][nr]);
        *(ushort4*)(W1t + (size_t)(n0 + nr) * 1024 + k0 + k4) = o;
    }
}

// ---------------------------------------------------------------- h = X@W1+b1 ; rope -> qr,kr (bf16); bias=(h@W2+b2)/2
__global__ __launch_bounds__(256) void fused_h_kernel(
    const float* __restrict__ X, const unsigned short* __restrict__ W1t,
    const float* __restrict__ b1, const float* __restrict__ W2,
    const float* __restrict__ b2,
    unsigned short* __restrict__ qr, unsigned short* __restrict__ kro,
    float* __restrict__ biasws)
{
    __shared__ __align__(16) unsigned short Xs[32 * 72];   // 32 rows x 64 k, pad 72
    __shared__ __align__(16) unsigned short Ws[128 * 72];  // 128 n x 64 k, pad 72
    __shared__ __align__(16) float hs[32 * 132];           // h tile fp32, pad 132
    __shared__ float W2s[128 * 24];
    __shared__ float b1s[128];
    __shared__ float b2s[24];

    const int t = threadIdx.x;
    const int row0 = blockIdx.x * 32;

    for (int i = t; i < 128 * 24; i += 256) W2s[i] = W2[i];
    if (t < 128) b1s[t] = b1[t];
    if (t < 24)  b2s[t] = b2[t];

    const int w = t >> 6, l = t & 63;
    const int lr = l & 15, lk = l >> 4;
    const int mrow0 = (w >> 1) * 16;     // 0 / 16
    const int ncol0 = (w & 1) * 64;      // 0 / 64

    f32x4 acc[4];
#pragma unroll
    for (int i = 0; i < 4; ++i) acc[i] = (f32x4){0.f, 0.f, 0.f, 0.f};

    const int xrow = t >> 3, xc8 = (t & 7) * 8;

    for (int kt = 0; kt < 16; ++kt) {
        __syncthreads();
        {   // stage X tile, fp32 -> bf16
            const float* sp = X + (size_t)(row0 + xrow) * 1024 + kt * 64 + xc8;
            float4 a = *(const float4*)sp;
            float4 b = *(const float4*)(sp + 4);
            unsigned short* dp = Xs + xrow * 72 + xc8;
            dp[0] = f2bf(a.x); dp[1] = f2bf(a.y); dp[2] = f2bf(a.z); dp[3] = f2bf(a.w);
            dp[4] = f2bf(b.x); dp[5] = f2bf(b.y); dp[6] = f2bf(b.z); dp[7] = f2bf(b.w);
        }
#pragma unroll
        for (int i = 0; i < 4; ++i) {   // stage W1t tile (bf16, already K-contiguous)
            int flat = i * 256 + t;             // 0..1023
            int wrow = flat >> 3, c8 = (flat & 7) * 8;
            *(uint4*)(Ws + wrow * 72 + c8) =
                *(const uint4*)(W1t + (size_t)wrow * 1024 + kt * 64 + c8);
        }
        __syncthreads();
#pragma unroll
        for (int ks = 0; ks < 2; ++ks) {
            bf16x8 af = *(const bf16x8*)(Xs + (mrow0 + lr) * 72 + ks * 32 + lk * 8);
#pragma unroll
            for (int t4 = 0; t4 < 4; ++t4) {
                bf16x8 bfv = *(const bf16x8*)(Ws + (ncol0 + t4 * 16 + lr) * 72 + ks * 32 + lk * 8);
                acc[t4] = __builtin_amdgcn_mfma_f32_16x16x32_bf16(af, bfv, acc[t4], 0, 0, 0);
            }
        }
    }

    // write h tile (C/D layout: col = lane&15, row = (lane>>4)*4 + reg)
#pragma unroll
    for (int t4 = 0; t4 < 4; ++t4) {
        int col = ncol0 + t4 * 16 + lr;
        float bb = b1s[col];
#pragma unroll
        for (int r = 0; r < 4; ++r)
            hs[(mrow0 + lk * 4 + r) * 132 + col] = acc[t4][r] + bb;
    }
    __syncthreads();

    // rope: q[j]=h[2j], k[j]=h[2j+1]; pairs (2i,2i+1) rotated by ang=pos*10000^(-i/32)
    {
        const int r = t >> 3;
        const int grow = row0 + r;
        const float pos = (float)(grow & 1023);
        const int i0 = (t & 7) * 4;
#pragma unroll
        for (int di = 0; di < 4; ++di) {
            int i = i0 + di;
            float invf = expf(-(float)i * 0.2878231366242557f);  // ln(10000)/32
            float sn, cs;
            sincosf(pos * invf, &sn, &cs);
            float q0 = hs[r * 132 + 4 * i + 0];
            float k0 = hs[r * 132 + 4 * i + 1];
            float q1 = hs[r * 132 + 4 * i + 2];
            float k1 = hs[r * 132 + 4 * i + 3];
            unsigned int qp = (unsigned int)f2bf(q0 * cs - q1 * sn)
                            | ((unsigned int)f2bf(q1 * cs + q0 * sn) << 16);
            unsigned int kp = (unsigned int)f2bf(k0 * cs - k1 * sn)
                            | ((unsigned int)f2bf(k1 * cs + k0 * sn) << 16);
            *(unsigned int*)(qr  + (size_t)grow * 64 + 2 * i) = qp;
            *(unsigned int*)(kro + (size_t)grow * 64 + 2 * i) = kp;
        }
    }

    // bias = (h @ W2 + b2) / 2   -> fp32 [8192][24]
#pragma unroll
    for (int ii = 0; ii < 3; ++ii) {
        int idx = ii * 256 + t;            // 0..767 = 32 rows x 24 cols
        int rr = idx / 24, cc = idx - rr * 24;
        float sum = 0.f;
        for (int kk = 0; kk < 128; ++kk)
            sum += hs[rr * 132 + kk] * W2s[kk * 24 + cc];
        biasws[(size_t)(row0 + rr) * 24 + cc] = (sum + b2s[cc]) * 0.5f;
    }
}

// ---------------------------------------------------------------- logits: att tile (MFMA) + 12 heads of bias/mask + write
__global__ __launch_bounds__(256) void logits_kernel(
    const unsigned short* __restrict__ qr, const unsigned short* __restrict__ kro,
    const float* __restrict__ biasws, const float* __restrict__ mask,
    float* __restrict__ out)
{
    __shared__ __align__(16) float att_s[64 * 68];
    __shared__ float bM[12 * 64];
    __shared__ float bN[12 * 64];
    __shared__ float mM[64];
    __shared__ float mN[64];

    const int nt = blockIdx.x, mt = blockIdx.y, b = blockIdx.z;
    const int t = threadIdx.x;

    for (int i = t; i < 768; i += 256) {
        int h = i >> 6, rr = i & 63;
        bM[i] = biasws[(size_t)(b * 1024 + mt * 64 + rr) * 24 + 2 * h];
        bN[i] = biasws[(size_t)(b * 1024 + nt * 64 + rr) * 24 + 2 * h + 1];
    }
    if (t < 64)       mM[t]      = mask[b * 1024 + mt * 64 + t];
    else if (t < 128) mN[t - 64] = mask[b * 1024 + nt * 64 + (t - 64)];

    const int w = t >> 6, l = t & 63;
    const int lr = l & 15, lk = l >> 4;
    const unsigned short* qp = qr  + (size_t)(b * 1024 + mt * 64 + w * 16 + lr) * 64 + lk * 8;
    const unsigned short* kp = kro + (size_t)(b * 1024 + nt * 64 + lr) * 64 + lk * 8;

    f32x4 acc[4];
#pragma unroll
    for (int i = 0; i < 4; ++i) acc[i] = (f32x4){0.f, 0.f, 0.f, 0.f};
#pragma unroll
    for (int ks = 0; ks < 2; ++ks) {
        bf16x8 af = *(const bf16x8*)(qp + ks * 32);
#pragma unroll
        for (int t4 = 0; t4 < 4; ++t4) {
            bf16x8 bfv = *(const bf16x8*)(kp + (size_t)t4 * 16 * 64 + ks * 32);
            acc[t4] = __builtin_amdgcn_mfma_f32_16x16x32_bf16(af, bfv, acc[t4], 0, 0, 0);
        }
    }
#pragma unroll
    for (int t4 = 0; t4 < 4; ++t4)
#pragma unroll
        for (int r = 0; r < 4; ++r)
            att_s[(w * 16 + lk * 4 + r) * 68 + t4 * 16 + lr] = acc[t4][r] * 0.125f;
    __syncthreads();

    // write phase: thread owns 1 row x 16 cols of the 64x64 tile
    const int r0 = t >> 2, c0 = (t & 3) * 16;
    const int m = mt * 64 + r0;
    const float pmv = mM[r0];
    float base[16], fixd[16];
    bool sel[16];
#pragma unroll
    for (int j = 0; j < 16; ++j) {
        int cc = c0 + j;
        int n = nt * 64 + cc;
        float tril = (n < m) ? 1.0e12f : 0.f;                 // strict lower triangle
        float pen  = (1.f - pmv * mN[cc]) * 1.0e12f;          // attention-mask penalty
        base[j] = att_s[r0 * 68 + cc] - tril - pen;
        fixd[j] = -10000.f - tril;                            // row-0/col-0 set, then tril
        sel[j]  = (m == 0) || (n == 0);
    }
    float* op0 = out + ((size_t)(b * 12) << 20) + ((size_t)m << 10) + nt * 64 + c0;
    for (int h = 0; h < 12; ++h) {
        float bm = bM[h * 64 + r0];
        float* op = op0 + ((size_t)h << 20);
#pragma unroll
        for (int j4 = 0; j4 < 4; ++j4) {
            float4 o;
            float* oe = (float*)&o;
#pragma unroll
            for (int e = 0; e < 4; ++e) {
                int j = j4 * 4 + e;
                float v = base[j] + bm + bN[h * 64 + c0 + j];
                oe[e] = sel[j] ? fixd[j] : v;
            }
            *(float4*)(op + j4 * 4) = o;
        }
    }
}

extern "C" void kernel_launch(void* const* d_in, const int* in_sizes, int n_in,
                              void* d_out, int out_size, void* d_ws, size_t ws_size,
                              hipStream_t stream)
{
    const float* X    = (const float*)d_in[0];
    const float* mask = (const float*)d_in[1];
    const float* W1   = (const float*)d_in[2];
    const float* b1   = (const float*)d_in[3];
    const float* W2   = (const float*)d_in[4];
    const float* b2   = (const float*)d_in[5];
    float* out = (float*)d_out;

    unsigned short* W1t = (unsigned short*)d_ws;                                  // 256 KB
    unsigned short* qr  = (unsigned short*)((char*)d_ws + 262144);                // 1 MB
    unsigned short* kro = (unsigned short*)((char*)d_ws + 262144 + 1048576);      // 1 MB
    float* biasws       = (float*)((char*)d_ws + 262144 + 2097152);               // 768 KB

    w1t_kernel<<<dim3(32, 4), 256, 0, stream>>>(W1, W1t);
    fused_h_kernel<<<256, 256, 0, stream>>>(X, W1t, b1, W2, b2, qr, kro, biasws);
    logits_kernel<<<dim3(16, 16, 8), 256, 0, stream>>>(qr, kro, biasws, mask, out);
}

// Round 3
// 450.987 us; speedup vs baseline: 1.1465x; 1.1465x over previous
//
#include <hip/hip_runtime.h>

typedef __attribute__((ext_vector_type(8))) short bf16x8;
typedef __attribute__((ext_vector_type(4))) float f32x4;

__device__ __forceinline__ unsigned short f2bf(float f) {
    unsigned int u = __builtin_bit_cast(unsigned int, f);
    u += 0x7FFFu + ((u >> 16) & 1u);   // round-to-nearest-even
    return (unsigned short)(u >> 16);
}

// ---------------------------------------------------------------- W1 -> bf16 transposed [128][1024]
__global__ __launch_bounds__(256) void w1t_kernel(const float* __restrict__ W1,
                                                  unsigned short* __restrict__ W1t) {
    __shared__ float tile[32][33];
    const int k0 = blockIdx.x * 32;   // 0..992
    const int n0 = blockIdx.y * 32;   // 0..96
    const int t = threadIdx.x;
    {
        int kr = t >> 3, n4 = (t & 7) * 4;
        float4 v = *(const float4*)(W1 + (size_t)(k0 + kr) * 128 + n0 + n4);
        tile[kr][n4 + 0] = v.x; tile[kr][n4 + 1] = v.y;
        tile[kr][n4 + 2] = v.z; tile[kr][n4 + 3] = v.w;
    }
    __syncthreads();
    {
        int nr = t >> 3, k4 = (t & 7) * 4;
        ushort4 o;
        o.x = f2bf(tile[k4 + 0][nr]);
        o.y = f2bf(tile[k4 + 1][nr]);
        o.z = f2bf(tile[k4 + 2][nr]);
        o.w = f2bf(tile[k4 + 3][nr]);
        *(ushort4*)(W1t + (size_t)(n0 + nr) * 1024 + k0 + k4) = o;
    }
}

// ---------------------------------------------------------------- h = X@W1+b1 ; rope -> qr,kr (bf16); bias=(h@W2+b2)/2
__global__ __launch_bounds__(256) void fused_h_kernel(
    const float* __restrict__ X, const unsigned short* __restrict__ W1t,
    const float* __restrict__ b1, const float* __restrict__ W2,
    const float* __restrict__ b2,
    unsigned short* __restrict__ qr, unsigned short* __restrict__ kro,
    float* __restrict__ biasws)
{
    __shared__ __align__(16) unsigned short Xs[32 * 72];   // 32 rows x 64 k, pad 72
    __shared__ __align__(16) unsigned short Ws[128 * 72];  // 128 n x 64 k, pad 72
    __shared__ __align__(16) float hs[32 * 132];           // h tile fp32, pad 132
    __shared__ float W2s[128 * 24];
    __shared__ float b1s[128];
    __shared__ float b2s[24];

    const int t = threadIdx.x;
    const int row0 = blockIdx.x * 32;

    for (int i = t; i < 128 * 24; i += 256) W2s[i] = W2[i];
    if (t < 128) b1s[t] = b1[t];
    if (t < 24)  b2s[t] = b2[t];

    const int w = t >> 6, l = t & 63;
    const int lr = l & 15, lk = l >> 4;
    const int mrow0 = (w >> 1) * 16;     // 0 / 16
    const int ncol0 = (w & 1) * 64;      // 0 / 64

    f32x4 acc[4];
#pragma unroll
    for (int i = 0; i < 4; ++i) acc[i] = (f32x4){0.f, 0.f, 0.f, 0.f};

    const int xrow = t >> 3, xc8 = (t & 7) * 8;

    for (int kt = 0; kt < 16; ++kt) {
        __syncthreads();
        {   // stage X tile, fp32 -> bf16
            const float* sp = X + (size_t)(row0 + xrow) * 1024 + kt * 64 + xc8;
            float4 a = *(const float4*)sp;
            float4 b = *(const float4*)(sp + 4);
            unsigned short* dp = Xs + xrow * 72 + xc8;
            dp[0] = f2bf(a.x); dp[1] = f2bf(a.y); dp[2] = f2bf(a.z); dp[3] = f2bf(a.w);
            dp[4] = f2bf(b.x); dp[5] = f2bf(b.y); dp[6] = f2bf(b.z); dp[7] = f2bf(b.w);
        }
#pragma unroll
        for (int i = 0; i < 4; ++i) {   // stage W1t tile (bf16, already K-contiguous)
            int flat = i * 256 + t;             // 0..1023
            int wrow = flat >> 3, c8 = (flat & 7) * 8;
            *(uint4*)(Ws + wrow * 72 + c8) =
                *(const uint4*)(W1t + (size_t)wrow * 1024 + kt * 64 + c8);
        }
        __syncthreads();
#pragma unroll
        for (int ks = 0; ks < 2; ++ks) {
            bf16x8 af = *(const bf16x8*)(Xs + (mrow0 + lr) * 72 + ks * 32 + lk * 8);
#pragma unroll
            for (int t4 = 0; t4 < 4; ++t4) {
                bf16x8 bfv = *(const bf16x8*)(Ws + (ncol0 + t4 * 16 + lr) * 72 + ks * 32 + lk * 8);
                acc[t4] = __builtin_amdgcn_mfma_f32_16x16x32_bf16(af, bfv, acc[t4], 0, 0, 0);
            }
        }
    }

    // write h tile (C/D layout: col = lane&15, row = (lane>>4)*4 + reg)
#pragma unroll
    for (int t4 = 0; t4 < 4; ++t4) {
        int col = ncol0 + t4 * 16 + lr;
        float bb = b1s[col];
#pragma unroll
        for (int r = 0; r < 4; ++r)
            hs[(mrow0 + lk * 4 + r) * 132 + col] = acc[t4][r] + bb;
    }
    __syncthreads();

    // rope: q[j]=h[2j], k[j]=h[2j+1]; pairs (2i,2i+1) rotated by ang=pos*10000^(-i/32)
    {
        const int r = t >> 3;
        const int grow = row0 + r;
        const float pos = (float)(grow & 1023);
        const int i0 = (t & 7) * 4;
#pragma unroll
        for (int di = 0; di < 4; ++di) {
            int i = i0 + di;
            float invf = expf(-(float)i * 0.2878231366242557f);  // ln(10000)/32
            float sn, cs;
            sincosf(pos * invf, &sn, &cs);
            float q0 = hs[r * 132 + 4 * i + 0];
            float k0 = hs[r * 132 + 4 * i + 1];
            float q1 = hs[r * 132 + 4 * i + 2];
            float k1 = hs[r * 132 + 4 * i + 3];
            unsigned int qp = (unsigned int)f2bf(q0 * cs - q1 * sn)
                            | ((unsigned int)f2bf(q1 * cs + q0 * sn) << 16);
            unsigned int kp = (unsigned int)f2bf(k0 * cs - k1 * sn)
                            | ((unsigned int)f2bf(k1 * cs + k0 * sn) << 16);
            *(unsigned int*)(qr  + (size_t)grow * 64 + 2 * i) = qp;
            *(unsigned int*)(kro + (size_t)grow * 64 + 2 * i) = kp;
        }
    }

    // bias = (h @ W2 + b2) / 2   -> fp32 [8192][24]
#pragma unroll
    for (int ii = 0; ii < 3; ++ii) {
        int idx = ii * 256 + t;            // 0..767 = 32 rows x 24 cols
        int rr = idx / 24, cc = idx - rr * 24;
        float sum = 0.f;
        for (int kk = 0; kk < 128; ++kk)
            sum += hs[rr * 132 + kk] * W2s[kk * 24 + cc];
        biasws[(size_t)(row0 + rr) * 24 + cc] = (sum + b2s[cc]) * 0.5f;
    }
}

// ---------------------------------------------------------------- logits: att tile (MFMA) + 12 heads of bias/mask + write
__global__ __launch_bounds__(256) void logits_kernel(
    const unsigned short* __restrict__ qr, const unsigned short* __restrict__ kro,
    const float* __restrict__ biasws, const float* __restrict__ mask,
    float* __restrict__ out)
{
    __shared__ __align__(16) float att_s[64 * 68];
    __shared__ __align__(16) float bM[12 * 64];
    __shared__ __align__(16) float bN[12 * 64];
    __shared__ float mMs[64];
    __shared__ float mNs[64];

    const int nt = blockIdx.x, mt = blockIdx.y, b = blockIdx.z;
    const int t = threadIdx.x;

    for (int i = t; i < 768; i += 256) {
        int h = i >> 6, rr = i & 63;
        bM[i] = biasws[(size_t)(b * 1024 + mt * 64 + rr) * 24 + 2 * h];
        bN[i] = biasws[(size_t)(b * 1024 + nt * 64 + rr) * 24 + 2 * h + 1];
    }
    if (t < 64)       mMs[t]      = mask[b * 1024 + mt * 64 + t];
    else if (t < 128) mNs[t - 64] = mask[b * 1024 + nt * 64 + (t - 64)];

    const int w = t >> 6, l = t & 63;
    const int lr = l & 15, lk = l >> 4;
    const unsigned short* qp = qr  + (size_t)(b * 1024 + mt * 64 + w * 16 + lr) * 64 + lk * 8;
    const unsigned short* kp = kro + (size_t)(b * 1024 + nt * 64 + lr) * 64 + lk * 8;

    f32x4 acc[4];
#pragma unroll
    for (int i = 0; i < 4; ++i) acc[i] = (f32x4){0.f, 0.f, 0.f, 0.f};
#pragma unroll
    for (int ks = 0; ks < 2; ++ks) {
        bf16x8 af = *(const bf16x8*)(qp + ks * 32);
#pragma unroll
        for (int t4 = 0; t4 < 4; ++t4) {
            bf16x8 bfv = *(const bf16x8*)(kp + (size_t)t4 * 16 * 64 + ks * 32);
            acc[t4] = __builtin_amdgcn_mfma_f32_16x16x32_bf16(af, bfv, acc[t4], 0, 0, 0);
        }
    }
#pragma unroll
    for (int t4 = 0; t4 < 4; ++t4)
#pragma unroll
        for (int r = 0; r < 4; ++r)
            att_s[(w * 16 + lk * 4 + r) * 68 + t4 * 16 + lr] = acc[t4][r] * 0.125f;
    __syncthreads();

    // ---------------- write phase: thread t -> cols (t&15)*4..+3, rows p*16 + (t>>4), p=0..3
    // A wave's store = 4 rows x 256B contiguous = 16 fully-covered 64B lines.
    const int u = t >> 4;          // row within 16-row group
    const int v = t & 15;          // col quad index
    const int c4 = v * 4;

    // per (pass, j) base = att - tril - maskpen  (head-independent)
    float base[4][4];
    float mN4[4];
    {
        float4 mn = *(const float4*)&mNs[c4];
        mN4[0] = mn.x; mN4[1] = mn.y; mN4[2] = mn.z; mN4[3] = mn.w;
    }
#pragma unroll
    for (int p = 0; p < 4; ++p) {
        const int row = p * 16 + u;
        const int m = mt * 64 + row;
        const float pmv = mMs[row];
        float4 a4 = *(const float4*)&att_s[row * 68 + c4];
        float av[4] = {a4.x, a4.y, a4.z, a4.w};
#pragma unroll
        for (int j = 0; j < 4; ++j) {
            int n = nt * 64 + c4 + j;
            float tril = (n < m) ? 1.0e12f : 0.f;
            float pen  = (1.f - pmv * mN4[j]) * 1.0e12f;
            base[p][j] = av[j] - tril - pen;
        }
    }

    float* outb = out + ((size_t)(b * 12) << 20) + ((size_t)(mt * 64 + u) << 10) + nt * 64 + c4;

    if (mt != 0 && nt != 0) {
        // fast path: no row-0/col-0 fixups
        for (int h = 0; h < 12; ++h) {
            float4 bn4 = *(const float4*)&bN[h * 64 + c4];
            float* oph = outb + ((size_t)h << 20);
#pragma unroll
            for (int p = 0; p < 4; ++p) {
                float bm = bM[h * 64 + p * 16 + u];
                f32x4 o;
                o.x = base[p][0] + bm + bn4.x;
                o.y = base[p][1] + bm + bn4.y;
                o.z = base[p][2] + bm + bn4.z;
                o.w = base[p][3] + bm + bn4.w;
                __builtin_nontemporal_store(o, (f32x4*)(oph + ((size_t)(p * 16) << 10)));
            }
        }
    } else {
        // slow path: apply row-0/col-0 -10000 sets (pre-tril), then tril
        float fixd[4][4];
        bool  sel[4][4];
#pragma unroll
        for (int p = 0; p < 4; ++p) {
            const int m = mt * 64 + p * 16 + u;
#pragma unroll
            for (int j = 0; j < 4; ++j) {
                int n = nt * 64 + c4 + j;
                fixd[p][j] = -10000.f - ((n < m) ? 1.0e12f : 0.f);
                sel[p][j]  = (m == 0) || (n == 0);
            }
        }
        for (int h = 0; h < 12; ++h) {
            float4 bn4 = *(const float4*)&bN[h * 64 + c4];
            float* oph = outb + ((size_t)h << 20);
#pragma unroll
            for (int p = 0; p < 4; ++p) {
                float bm = bM[h * 64 + p * 16 + u];
                f32x4 o;
                o.x = sel[p][0] ? fixd[p][0] : (base[p][0] + bm + bn4.x);
                o.y = sel[p][1] ? fixd[p][1] : (base[p][1] + bm + bn4.y);
                o.z = sel[p][2] ? fixd[p][2] : (base[p][2] + bm + bn4.z);
                o.w = sel[p][3] ? fixd[p][3] : (base[p][3] + bm + bn4.w);
                __builtin_nontemporal_store(o, (f32x4*)(oph + ((size_t)(p * 16) << 10)));
            }
        }
    }
}

extern "C" void kernel_launch(void* const* d_in, const int* in_sizes, int n_in,
                              void* d_out, int out_size, void* d_ws, size_t ws_size,
                              hipStream_t stream)
{
    const float* X    = (const float*)d_in[0];
    const float* mask = (const float*)d_in[1];
    const float* W1   = (const float*)d_in[2];
    const float* b1   = (const float*)d_in[3];
    const float* W2   = (const float*)d_in[4];
    const float* b2   = (const float*)d_in[5];
    float* out = (float*)d_out;

    unsigned short* W1t = (unsigned short*)d_ws;                                  // 256 KB
    unsigned short* qr  = (unsigned short*)((char*)d_ws + 262144);                // 1 MB
    unsigned short* kro = (unsigned short*)((char*)d_ws + 262144 + 1048576);      // 1 MB
    float* biasws       = (float*)((char*)d_ws + 262144 + 2097152);               // 768 KB

    w1t_kernel<<<dim3(32, 4), 256, 0, stream>>>(W1, W1t);
    fused_h_kernel<<<256, 256, 0, stream>>>(X, W1t, b1, W2, b2, qr, kro, biasws);
    logits_kernel<<<dim3(16, 16, 8), 256, 0, stream>>>(qr, kro, biasws, mask, out);
}